// Round 9
// baseline (178.006 us; speedup 1.0000x reference)
//
#include <hip/hip_runtime.h>
#include <hip/hip_bf16.h>

// HeadLayer: B=8, S=2048, E=1024, H=64.
// Inputs (fp32): x[B,S,E], Wq[E,H], Wk[E,H], Wv[E,H]. Output (fp32): [B,S,H].
// ws (bf16): qb[B,S,H] (pre-scaled 1/32), kb[B,S,H], vtb[B,H,S], Wt[192][1024].

#define BATCH 8
#define SEQ   2048
#define EMB   1024
#define HD    64
#define ROWS  (BATCH*SEQ)      // 16384
#define NTOT  192

typedef __attribute__((ext_vector_type(8))) short short8;   // 8 bf16 (4 VGPR)
typedef __attribute__((ext_vector_type(4))) float floatx4;  // MFMA C/D frag

static __device__ __forceinline__ short f2bf(float f) {
  union { __hip_bfloat16 h; short s; } u;
  u.h = __float2bfloat16(f);
  return u.s;
}

static __device__ __forceinline__ short8 pack8(float4 u, float4 v) {
  short8 r;
  r[0] = f2bf(u.x); r[1] = f2bf(u.y); r[2] = f2bf(u.z); r[3] = f2bf(u.w);
  r[4] = f2bf(v.x); r[5] = f2bf(v.y); r[6] = f2bf(v.z); r[7] = f2bf(v.w);
  return r;
}

// ---------------- W transpose pre-pass --------------------------------------
__global__ __launch_bounds__(256) void wt_kernel(
    const float* __restrict__ Wq, const float* __restrict__ Wk,
    const float* __restrict__ Wv, short* __restrict__ Wt) {
  const int i = blockIdx.x * 256 + threadIdx.x;   // 0..49151
  const int np = i % NTOT;
  const int c4 = i / NTOT;                        // 0..255
  const float* __restrict__ W = (np < 64) ? Wq : ((np < 128) ? Wk : Wv);
  const int n = np & 63;
  short4 o;
  o.x = f2bf(W[(c4 * 4 + 0) * HD + n]);
  o.y = f2bf(W[(c4 * 4 + 1) * HD + n]);
  o.z = f2bf(W[(c4 * 4 + 2) * HD + n]);
  o.w = f2bf(W[(c4 * 4 + 3) * HD + n]);
  *(short4*)(Wt + (size_t)np * EMB + c4 * 4) = o;
}

// ---------------- MFMA QKV projection: no LDS, no barriers ------------------
// Grid 512 (2 blocks/CU, 8 waves/CU). Block = 32 rows x 192 cols, full K.
// Wave w: both m-frags x n-tiles 3w..3w+2 (6 acc). A loaded straight from
// global in k-blocks of 128 (16 float4/lane), register double-buffered with
// STATIC indices only; B (12 short8/k-block) from L2-hot Wt. Waves free-run:
// no drain points, 28 loads in flight per wave. Intra-block 4x A redundancy
// is served by L1/L2 (same lines, same window); HBM fetch stays ~64 MB.
__global__ __launch_bounds__(256, 2) void proj_kernel(
    const float* __restrict__ x, const short* __restrict__ Wt,
    short* __restrict__ qb, short* __restrict__ kb_, short* __restrict__ vtb) {
  const int t = threadIdx.x, lane = t & 63, w = t >> 6;
  const int lo = lane & 15, quad = lane >> 4;
  const int m0 = blockIdx.x * 32;

  const float* __restrict__ xr0 = x + (size_t)(m0 + lo) * EMB + quad * 8;
  const float* __restrict__ xr1 = xr0 + (size_t)16 * EMB;
  const short* __restrict__ wb = Wt + (size_t)(w * 48 + lo) * EMB + quad * 8;

  floatx4 acc[2][3];
#pragma unroll
  for (int mf = 0; mf < 2; ++mf)
#pragma unroll
    for (int j = 0; j < 3; ++j) acc[mf][j] = (floatx4){0.f, 0.f, 0.f, 0.f};

  // A k-block buffers: [s][part]  part0/1 = row lo cols +0/+4, part2/3 = row lo+16
  float4 A0[4][4], A1[4][4];
  short8 Bc[4][3];

  // preload k-block 0 -> A0
#pragma unroll
  for (int s = 0; s < 4; ++s) {
    A0[s][0] = *(const float4*)(xr0 + s * 32);
    A0[s][1] = *(const float4*)(xr0 + s * 32 + 4);
    A0[s][2] = *(const float4*)(xr1 + s * 32);
    A0[s][3] = *(const float4*)(xr1 + s * 32 + 4);
  }

  for (int kb = 0; kb < 8; kb += 2) {
    // ---- even half: B(kb), prefetch A(kb+1) -> A1, compute A0
    {
      const int ko = kb * 128;
#pragma unroll
      for (int s = 0; s < 4; ++s) {
        Bc[s][0] = *(const short8*)(wb + ko + s * 32);
        Bc[s][1] = *(const short8*)(wb + ko + s * 32 + (size_t)16 * EMB);
        Bc[s][2] = *(const short8*)(wb + ko + s * 32 + (size_t)32 * EMB);
      }
#pragma unroll
      for (int s = 0; s < 4; ++s) {
        A1[s][0] = *(const float4*)(xr0 + ko + 128 + s * 32);
        A1[s][1] = *(const float4*)(xr0 + ko + 128 + s * 32 + 4);
        A1[s][2] = *(const float4*)(xr1 + ko + 128 + s * 32);
        A1[s][3] = *(const float4*)(xr1 + ko + 128 + s * 32 + 4);
      }
#pragma unroll
      for (int s = 0; s < 4; ++s) {
        const short8 af0 = pack8(A0[s][0], A0[s][1]);
        const short8 af1 = pack8(A0[s][2], A0[s][3]);
        acc[0][0] = __builtin_amdgcn_mfma_f32_16x16x32_bf16(af0, Bc[s][0], acc[0][0], 0, 0, 0);
        acc[1][0] = __builtin_amdgcn_mfma_f32_16x16x32_bf16(af1, Bc[s][0], acc[1][0], 0, 0, 0);
        acc[0][1] = __builtin_amdgcn_mfma_f32_16x16x32_bf16(af0, Bc[s][1], acc[0][1], 0, 0, 0);
        acc[1][1] = __builtin_amdgcn_mfma_f32_16x16x32_bf16(af1, Bc[s][1], acc[1][1], 0, 0, 0);
        acc[0][2] = __builtin_amdgcn_mfma_f32_16x16x32_bf16(af0, Bc[s][2], acc[0][2], 0, 0, 0);
        acc[1][2] = __builtin_amdgcn_mfma_f32_16x16x32_bf16(af1, Bc[s][2], acc[1][2], 0, 0, 0);
      }
    }
    // ---- odd half: B(kb+1), prefetch A(kb+2) -> A0, compute A1
    {
      const int ko = kb * 128 + 128;
#pragma unroll
      for (int s = 0; s < 4; ++s) {
        Bc[s][0] = *(const short8*)(wb + ko + s * 32);
        Bc[s][1] = *(const short8*)(wb + ko + s * 32 + (size_t)16 * EMB);
        Bc[s][2] = *(const short8*)(wb + ko + s * 32 + (size_t)32 * EMB);
      }
      if (kb + 2 < 8) {
#pragma unroll
        for (int s = 0; s < 4; ++s) {
          A0[s][0] = *(const float4*)(xr0 + ko + 128 + s * 32);
          A0[s][1] = *(const float4*)(xr0 + ko + 128 + s * 32 + 4);
          A0[s][2] = *(const float4*)(xr1 + ko + 128 + s * 32);
          A0[s][3] = *(const float4*)(xr1 + ko + 128 + s * 32 + 4);
        }
      }
#pragma unroll
      for (int s = 0; s < 4; ++s) {
        const short8 af0 = pack8(A1[s][0], A1[s][1]);
        const short8 af1 = pack8(A1[s][2], A1[s][3]);
        acc[0][0] = __builtin_amdgcn_mfma_f32_16x16x32_bf16(af0, Bc[s][0], acc[0][0], 0, 0, 0);
        acc[1][0] = __builtin_amdgcn_mfma_f32_16x16x32_bf16(af1, Bc[s][0], acc[1][0], 0, 0, 0);
        acc[0][1] = __builtin_amdgcn_mfma_f32_16x16x32_bf16(af0, Bc[s][1], acc[0][1], 0, 0, 0);
        acc[1][1] = __builtin_amdgcn_mfma_f32_16x16x32_bf16(af1, Bc[s][1], acc[1][1], 0, 0, 0);
        acc[0][2] = __builtin_amdgcn_mfma_f32_16x16x32_bf16(af0, Bc[s][2], acc[0][2], 0, 0, 0);
        acc[1][2] = __builtin_amdgcn_mfma_f32_16x16x32_bf16(af1, Bc[s][2], acc[1][2], 0, 0, 0);
      }
    }
  }

  // ---- epilogue: wave-private n-tiles, direct stores (no reduction)
  const int bb = m0 >> 11;
  const int sbase = (m0 & (SEQ - 1)) + quad * 4;
#pragma unroll
  for (int mf = 0; mf < 2; ++mf) {
    const int rowb = m0 + mf * 16 + quad * 4;
#pragma unroll
    for (int j = 0; j < 3; ++j) {
      const int nt = w * 3 + j;
      const floatx4 v = acc[mf][j];
      if (nt < 4) {
#pragma unroll
        for (int r = 0; r < 4; ++r)
          qb[(size_t)(rowb + r) * HD + nt * 16 + lo] = f2bf(v[r] * 0.03125f);
      } else if (nt < 8) {
#pragma unroll
        for (int r = 0; r < 4; ++r)
          kb_[(size_t)(rowb + r) * HD + (nt - 4) * 16 + lo] = f2bf(v[r]);
      } else {
        const int col = (nt - 8) * 16 + lo;
        short4 sv = make_short4(f2bf(v[0]), f2bf(v[1]), f2bf(v[2]), f2bf(v[3]));
        *(short4*)(vtb + ((size_t)bb * HD + col) * SEQ + sbase + mf * 16) = sv;
      }
    }
  }
}

// ---------------- MFMA flash attention, key-half split (unchanged R6) -------
#define KSTR 72
#define PSTR 40

__global__ __launch_bounds__(256, 2) void attn_kernel(
    const short* __restrict__ qb, const short* __restrict__ kb,
    const short* __restrict__ vtb, float* __restrict__ out) {
  __shared__ __align__(16) short Ks[2][64 * KSTR];
  __shared__ __align__(16) short Vs[2][64 * KSTR];
  __shared__ __align__(16) short Ps[4][16 * PSTR];
  __shared__ __align__(16) floatx4 Red[2][5][64];

  const int b = blockIdx.y;
  const int bx = blockIdx.x;
  const int qx = (bx & 1) ? (63 - (bx >> 1)) : (bx >> 1);  // pair light+heavy
  const int q0 = qx * 32;
  const int t = threadIdx.x, lane = t & 63, w = t >> 6;
  const int wr = w >> 1, wk = w & 1;
  const int lo = lane & 15, quad = lane >> 4;

  const short* qp = qb + ((size_t)b * SEQ + q0 + wr * 16 + lo) * HD + quad * 8;
  const short8 qf0 = *(const short8*)(qp);
  const short8 qf1 = *(const short8*)(qp + 32);

  const int r0 = t >> 3, c0 = (t & 7) * 8;
  const int r1 = r0 + 32;
  const short* __restrict__ kgb = kb + (size_t)b * SEQ * HD;
  const short* __restrict__ vgb = vtb + (size_t)b * HD * SEQ;

  floatx4 acc[4];
  float lsum[4] = {0.f, 0.f, 0.f, 0.f};
#pragma unroll
  for (int nt = 0; nt < 4; ++nt) acc[nt] = (floatx4){0.f, 0.f, 0.f, 0.f};

  {
    short8 k0v = *(const short8*)(kgb + (size_t)r0 * HD + c0);
    short8 k1v = *(const short8*)(kgb + (size_t)r1 * HD + c0);
    short8 v0v = *(const short8*)(vgb + (size_t)r0 * SEQ + c0);
    short8 v1v = *(const short8*)(vgb + (size_t)r1 * SEQ + c0);
    *(short8*)(&Ks[0][r0 * KSTR + c0]) = k0v;
    *(short8*)(&Ks[0][r1 * KSTR + c0]) = k1v;
    *(short8*)(&Vs[0][r0 * KSTR + c0]) = v0v;
    *(short8*)(&Vs[0][r1 * KSTR + c0]) = v1v;
  }

  const int niter = q0 / 64 + 1;
  for (int it = 0; it < niter; ++it) {
    const int j0 = it * 64;
    const int buf = it & 1;
    __syncthreads();

    short8 kfr[2][2], vfr[4];
#pragma unroll
    for (int n2 = 0; n2 < 2; ++n2) {
      const short* kr = &Ks[buf][(wk * 32 + n2 * 16 + lo) * KSTR + quad * 8];
      kfr[n2][0] = *(const short8*)(kr);
      kfr[n2][1] = *(const short8*)(kr + 32);
    }
#pragma unroll
    for (int nt = 0; nt < 4; ++nt)
      vfr[nt] = *(const short8*)(&Vs[buf][(nt * 16 + lo) * KSTR + wk * 32 + quad * 8]);

    short8 nk0, nk1, nv0, nv1;
    const bool more = (it + 1 < niter);
    if (more) {
      const int jn = j0 + 64;
      nk0 = *(const short8*)(kgb + (size_t)(jn + r0) * HD + c0);
      nk1 = *(const short8*)(kgb + (size_t)(jn + r1) * HD + c0);
      nv0 = *(const short8*)(vgb + (size_t)r0 * SEQ + jn + c0);
      nv1 = *(const short8*)(vgb + (size_t)r1 * SEQ + jn + c0);
    }

    floatx4 s0 = (floatx4){0.f, 0.f, 0.f, 0.f};
    floatx4 s1 = (floatx4){0.f, 0.f, 0.f, 0.f};
    s0 = __builtin_amdgcn_mfma_f32_16x16x32_bf16(qf0, kfr[0][0], s0, 0, 0, 0);
    s0 = __builtin_amdgcn_mfma_f32_16x16x32_bf16(qf1, kfr[0][1], s0, 0, 0, 0);
    s1 = __builtin_amdgcn_mfma_f32_16x16x32_bf16(qf0, kfr[1][0], s1, 0, 0, 0);
    s1 = __builtin_amdgcn_mfma_f32_16x16x32_bf16(qf1, kfr[1][1], s1, 0, 0, 0);

    const bool diag = (j0 + 64 > q0);
    const int rowb = q0 + wr * 16 + quad * 4;
    short* Pw = Ps[w];
#pragma unroll
    for (int r = 0; r < 4; ++r) {
      float e0 = __expf(s0[r]);
      float e1 = __expf(s1[r]);
      if (diag) {
        const int key0 = j0 + wk * 32 + lo;
        e0 = (key0 <= rowb + r) ? e0 : 0.f;
        e1 = (key0 + 16 <= rowb + r) ? e1 : 0.f;
      }
      lsum[r] += e0 + e1;
      Pw[(quad * 4 + r) * PSTR + lo] = f2bf(e0);
      Pw[(quad * 4 + r) * PSTR + 16 + lo] = f2bf(e1);
    }
    const short8 pf = *(const short8*)(&Pw[lo * PSTR + quad * 8]);
#pragma unroll
    for (int nt = 0; nt < 4; ++nt)
      acc[nt] = __builtin_amdgcn_mfma_f32_16x16x32_bf16(pf, vfr[nt], acc[nt], 0, 0, 0);

    if (more) {
      const int nb = buf ^ 1;
      *(short8*)(&Ks[nb][r0 * KSTR + c0]) = nk0;
      *(short8*)(&Ks[nb][r1 * KSTR + c0]) = nk1;
      *(short8*)(&Vs[nb][r0 * KSTR + c0]) = nv0;
      *(short8*)(&Vs[nb][r1 * KSTR + c0]) = nv1;
    }
  }

#pragma unroll
  for (int d = 1; d < 16; d <<= 1) {
#pragma unroll
    for (int r = 0; r < 4; ++r) lsum[r] += __shfl_xor(lsum[r], d);
  }

  if (wk == 1) {
#pragma unroll
    for (int nt = 0; nt < 4; ++nt) Red[wr][nt][lane] = acc[nt];
    Red[wr][4][lane] = (floatx4){lsum[0], lsum[1], lsum[2], lsum[3]};
  }
  __syncthreads();
  if (wk == 0) {
    const floatx4 lp = Red[wr][4][lane];
    const int rowb = q0 + wr * 16 + quad * 4;
#pragma unroll
    for (int nt = 0; nt < 4; ++nt) {
      const floatx4 o = acc[nt] + Red[wr][nt][lane];
#pragma unroll
      for (int r = 0; r < 4; ++r)
        out[((size_t)b * SEQ + rowb + r) * HD + nt * 16 + lo] =
            o[r] / (lsum[r] + lp[r]);
    }
  }
}

extern "C" void kernel_launch(void* const* d_in, const int* in_sizes, int n_in,
                              void* d_out, int out_size, void* d_ws, size_t ws_size,
                              hipStream_t stream) {
  const float* x  = (const float*)d_in[0];
  const float* Wq = (const float*)d_in[1];
  const float* Wk = (const float*)d_in[2];
  const float* Wv = (const float*)d_in[3];
  float* out = (float*)d_out;
  short* ws = (short*)d_ws;
  short* qbp = ws;
  short* kbp = ws + (size_t)ROWS * HD;
  short* vtp = ws + (size_t)2 * ROWS * HD;
  short* Wt  = ws + (size_t)3 * ROWS * HD;   // total 6.68 MB <= ws_size

  wt_kernel<<<dim3(NTOT), 256, 0, stream>>>(Wq, Wk, Wv, Wt);
  proj_kernel<<<dim3(ROWS / 32), 256, 0, stream>>>(x, Wt, qbp, kbp, vtp);
  attn_kernel<<<dim3(SEQ / 32, BATCH), 256, 0, stream>>>(qbp, kbp, vtp, out);
}

// Round 10
// 144.960 us; speedup vs baseline: 1.2280x; 1.2280x over previous
//
#include <hip/hip_runtime.h>
#include <hip/hip_bf16.h>

// HeadLayer: B=8, S=2048, E=1024, H=64.
// Inputs (fp32): x[B,S,E], Wq[E,H], Wk[E,H], Wv[E,H]. Output (fp32): [B,S,H].
// ws (bf16): qb[B,S,H] (pre-scaled 1/32), kb[B,S,H], vtb[B,H,S],
//            Wts[16][192][64] (pre-tiled, XOR-swizzled B tiles).

#define BATCH 8
#define SEQ   2048
#define EMB   1024
#define HD    64
#define ROWS  (BATCH*SEQ)      // 16384
#define NTOT  192
#define BK    64
#define NKT   (EMB / BK)       // 16

typedef __attribute__((ext_vector_type(8))) short short8;   // 8 bf16 (4 VGPR)
typedef __attribute__((ext_vector_type(4))) float floatx4;  // MFMA C/D frag

static __device__ __forceinline__ short f2bf(float f) {
  union { __hip_bfloat16 h; short s; } u;
  u.h = __float2bfloat16(f);
  return u.s;
}

static __device__ __forceinline__ short8 pack8(float4 u, float4 v) {
  short8 r;
  r[0] = f2bf(u.x); r[1] = f2bf(u.y); r[2] = f2bf(u.z); r[3] = f2bf(u.w);
  r[4] = f2bf(v.x); r[5] = f2bf(v.y); r[6] = f2bf(v.z); r[7] = f2bf(v.w);
  return r;
}

// async global->LDS, 16 B per lane; LDS dest = wave-uniform base + lane*16
static __device__ __forceinline__ void gload_lds16(const void* g, void* l) {
  __builtin_amdgcn_global_load_lds(
      (const __attribute__((address_space(1))) unsigned int*)g,
      (__attribute__((address_space(3))) unsigned int*)l, 16, 0, 0);
}

// ---------------- W pre-pass: tiled + swizzled B ----------------------------
// Wts[kt][np][slot s][u] = W_logical[np][kt*64 + (s^(np&7))*8 + u]
// where W_logical[np][k] = Wsrc[k*HD + (np&63)], Wsrc per np-range.
// 24576 slots of 8 bf16; grid 96 x 256.
__global__ __launch_bounds__(256) void wt_kernel(
    const float* __restrict__ Wq, const float* __restrict__ Wk,
    const float* __restrict__ Wv, short* __restrict__ Wts) {
  const int id = blockIdx.x * 256 + threadIdx.x;   // 0..24575
  const int kt = id / 1536;
  const int rem = id - kt * 1536;
  const int np = rem >> 3;
  const int s = rem & 7;
  const float* __restrict__ W = (np < 64) ? Wq : ((np < 128) ? Wk : Wv);
  const int n = np & 63;
  const int k0 = kt * BK + (s ^ (np & 7)) * 8;
  short8 o;
#pragma unroll
  for (int u = 0; u < 8; ++u) o[u] = f2bf(W[(size_t)(k0 + u) * HD + n]);
  *(short8*)(Wts + (size_t)id * 8) = o;
}

// ---------------- MFMA QKV projection: m97-style global_load_lds ------------
// Grid 512 (2 blocks/CU, 8 waves/CU). Block = 32 rows x 192 cols, full K.
// Per k-tile (BK=64): stage A 8 KB (fp32, XOR-swizzled via per-lane global
// addrs) + B 24 KB (straight copy of pre-swizzled Wts tile) with
// global_load_lds width=16 (8 instr/wave); barrier; frags + 12 MFMA/wave;
// barrier. Swizzle: LDS slot j of row r holds global chunk j^(r&7) ->
// frag reads are 2-way (free); staging stays segment-coalesced.
__global__ __launch_bounds__(256, 2) void proj_kernel(
    const float* __restrict__ x, const short* __restrict__ Wts,
    short* __restrict__ qb, short* __restrict__ kb_, short* __restrict__ vtb) {
  __shared__ __align__(16) float As[32 * 64];    // 8 KB
  __shared__ __align__(16) short Bs[192 * 64];   // 24 KB

  const int t = threadIdx.x, lane = t & 63, w = t >> 6;
  const int lo = lane & 15, quad = lane >> 4;
  const int e = lo & 7;
  const int m0 = blockIdx.x * 32;

  // A staging: 2 chunks/wave, chunk = 4 rows x 256 B; lane -> row,slot
  const int cc0 = w * 2, cc1 = cc0 + 1;
  const int ar0 = cc0 * 4 + (lane >> 4);
  const int ar1 = cc1 * 4 + (lane >> 4);
  const int aj = lane & 15;
  const float* agp0 = x + (size_t)(m0 + ar0) * EMB + ((aj ^ (ar0 & 7)) * 4);
  const float* agp1 = x + (size_t)(m0 + ar1) * EMB + ((aj ^ (ar1 & 7)) * 4);
  float* alp0 = As + cc0 * 256;   // wave-uniform
  float* alp1 = As + cc1 * 256;

  // B staging: 6 chunks/wave, straight copy from pre-swizzled tile
  const short* bgp = Wts + (size_t)(w * 6) * 512 + lane * 8;
  short* blp = Bs + (w * 6) * 512;

  floatx4 acc[2][3];
#pragma unroll
  for (int mf = 0; mf < 2; ++mf)
#pragma unroll
    for (int j = 0; j < 3; ++j) acc[mf][j] = (floatx4){0.f, 0.f, 0.f, 0.f};

  for (int kt = 0; kt < NKT; ++kt) {
    __syncthreads();   // all waves done reading previous tile's frags
    // ---- stage (async DMA; completion enforced by next barrier's vmcnt)
    gload_lds16(agp0 + kt * BK, alp0);
    gload_lds16(agp1 + kt * BK, alp1);
    const short* bg = bgp + (size_t)kt * 12288;
#pragma unroll
    for (int i = 0; i < 6; ++i)
      gload_lds16(bg + i * 512, blp + i * 512);
    __syncthreads();   // staging drained + visible

    // ---- A frags: row mf*16+lo, slots (8ks+2q+h)^e  (2-way conflicts: free)
    short8 af[2][2];
#pragma unroll
    for (int mf = 0; mf < 2; ++mf) {
      const float* Ar = As + (mf * 16 + lo) * 64;
#pragma unroll
      for (int ks = 0; ks < 2; ++ks) {
        const float4 f0 = *(const float4*)(Ar + (((8 * ks + 2 * quad) ^ e) << 2));
        const float4 f1 = *(const float4*)(Ar + (((8 * ks + 2 * quad + 1) ^ e) << 2));
        af[mf][ks] = pack8(f0, f1);
      }
    }
    // ---- B frags: row (3w+j)*16+lo, slot (4ks+q)^e
    short8 bf[3][2];
#pragma unroll
    for (int j = 0; j < 3; ++j) {
      const short* Br = Bs + ((w * 3 + j) * 16 + lo) * 64;
#pragma unroll
      for (int ks = 0; ks < 2; ++ks)
        bf[j][ks] = *(const short8*)(Br + (((4 * ks + quad) ^ e) << 3));
    }
#pragma unroll
    for (int ks = 0; ks < 2; ++ks)
#pragma unroll
      for (int j = 0; j < 3; ++j) {
        acc[0][j] = __builtin_amdgcn_mfma_f32_16x16x32_bf16(af[0][ks], bf[j][ks], acc[0][j], 0, 0, 0);
        acc[1][j] = __builtin_amdgcn_mfma_f32_16x16x32_bf16(af[1][ks], bf[j][ks], acc[1][j], 0, 0, 0);
      }
  }

  // ---- epilogue: wave-private n-tiles, direct stores
  const int bb = m0 >> 11;
  const int sbase = (m0 & (SEQ - 1)) + quad * 4;
#pragma unroll
  for (int mf = 0; mf < 2; ++mf) {
    const int rowb = m0 + mf * 16 + quad * 4;
#pragma unroll
    for (int j = 0; j < 3; ++j) {
      const int nt = w * 3 + j;
      const floatx4 v = acc[mf][j];
      if (nt < 4) {
#pragma unroll
        for (int r = 0; r < 4; ++r)
          qb[(size_t)(rowb + r) * HD + nt * 16 + lo] = f2bf(v[r] * 0.03125f);
      } else if (nt < 8) {
#pragma unroll
        for (int r = 0; r < 4; ++r)
          kb_[(size_t)(rowb + r) * HD + (nt - 4) * 16 + lo] = f2bf(v[r]);
      } else {
        const int col = (nt - 8) * 16 + lo;
        short4 sv = make_short4(f2bf(v[0]), f2bf(v[1]), f2bf(v[2]), f2bf(v[3]));
        *(short4*)(vtb + ((size_t)bb * HD + col) * SEQ + sbase + mf * 16) = sv;
      }
    }
  }
}

// ---------------- MFMA flash attention, key-half split (unchanged R6) -------
#define KSTR 72
#define PSTR 40

__global__ __launch_bounds__(256, 2) void attn_kernel(
    const short* __restrict__ qb, const short* __restrict__ kb,
    const short* __restrict__ vtb, float* __restrict__ out) {
  __shared__ __align__(16) short Ks[2][64 * KSTR];
  __shared__ __align__(16) short Vs[2][64 * KSTR];
  __shared__ __align__(16) short Ps[4][16 * PSTR];
  __shared__ __align__(16) floatx4 Red[2][5][64];

  const int b = blockIdx.y;
  const int bx = blockIdx.x;
  const int qx = (bx & 1) ? (63 - (bx >> 1)) : (bx >> 1);  // pair light+heavy
  const int q0 = qx * 32;
  const int t = threadIdx.x, lane = t & 63, w = t >> 6;
  const int wr = w >> 1, wk = w & 1;
  const int lo = lane & 15, quad = lane >> 4;

  const short* qp = qb + ((size_t)b * SEQ + q0 + wr * 16 + lo) * HD + quad * 8;
  const short8 qf0 = *(const short8*)(qp);
  const short8 qf1 = *(const short8*)(qp + 32);

  const int r0 = t >> 3, c0 = (t & 7) * 8;
  const int r1 = r0 + 32;
  const short* __restrict__ kgb = kb + (size_t)b * SEQ * HD;
  const short* __restrict__ vgb = vtb + (size_t)b * HD * SEQ;

  floatx4 acc[4];
  float lsum[4] = {0.f, 0.f, 0.f, 0.f};
#pragma unroll
  for (int nt = 0; nt < 4; ++nt) acc[nt] = (floatx4){0.f, 0.f, 0.f, 0.f};

  {
    short8 k0v = *(const short8*)(kgb + (size_t)r0 * HD + c0);
    short8 k1v = *(const short8*)(kgb + (size_t)r1 * HD + c0);
    short8 v0v = *(const short8*)(vgb + (size_t)r0 * SEQ + c0);
    short8 v1v = *(const short8*)(vgb + (size_t)r1 * SEQ + c0);
    *(short8*)(&Ks[0][r0 * KSTR + c0]) = k0v;
    *(short8*)(&Ks[0][r1 * KSTR + c0]) = k1v;
    *(short8*)(&Vs[0][r0 * KSTR + c0]) = v0v;
    *(short8*)(&Vs[0][r1 * KSTR + c0]) = v1v;
  }

  const int niter = q0 / 64 + 1;
  for (int it = 0; it < niter; ++it) {
    const int j0 = it * 64;
    const int buf = it & 1;
    __syncthreads();

    short8 kfr[2][2], vfr[4];
#pragma unroll
    for (int n2 = 0; n2 < 2; ++n2) {
      const short* kr = &Ks[buf][(wk * 32 + n2 * 16 + lo) * KSTR + quad * 8];
      kfr[n2][0] = *(const short8*)(kr);
      kfr[n2][1] = *(const short8*)(kr + 32);
    }
#pragma unroll
    for (int nt = 0; nt < 4; ++nt)
      vfr[nt] = *(const short8*)(&Vs[buf][(nt * 16 + lo) * KSTR + wk * 32 + quad * 8]);

    short8 nk0, nk1, nv0, nv1;
    const bool more = (it + 1 < niter);
    if (more) {
      const int jn = j0 + 64;
      nk0 = *(const short8*)(kgb + (size_t)(jn + r0) * HD + c0);
      nk1 = *(const short8*)(kgb + (size_t)(jn + r1) * HD + c0);
      nv0 = *(const short8*)(vgb + (size_t)r0 * SEQ + jn + c0);
      nv1 = *(const short8*)(vgb + (size_t)r1 * SEQ + jn + c0);
    }

    floatx4 s0 = (floatx4){0.f, 0.f, 0.f, 0.f};
    floatx4 s1 = (floatx4){0.f, 0.f, 0.f, 0.f};
    s0 = __builtin_amdgcn_mfma_f32_16x16x32_bf16(qf0, kfr[0][0], s0, 0, 0, 0);
    s0 = __builtin_amdgcn_mfma_f32_16x16x32_bf16(qf1, kfr[0][1], s0, 0, 0, 0);
    s1 = __builtin_amdgcn_mfma_f32_16x16x32_bf16(qf0, kfr[1][0], s1, 0, 0, 0);
    s1 = __builtin_amdgcn_mfma_f32_16x16x32_bf16(qf1, kfr[1][1], s1, 0, 0, 0);

    const bool diag = (j0 + 64 > q0);
    const int rowb = q0 + wr * 16 + quad * 4;
    short* Pw = Ps[w];
#pragma unroll
    for (int r = 0; r < 4; ++r) {
      float e0 = __expf(s0[r]);
      float e1 = __expf(s1[r]);
      if (diag) {
        const int key0 = j0 + wk * 32 + lo;
        e0 = (key0 <= rowb + r) ? e0 : 0.f;
        e1 = (key0 + 16 <= rowb + r) ? e1 : 0.f;
      }
      lsum[r] += e0 + e1;
      Pw[(quad * 4 + r) * PSTR + lo] = f2bf(e0);
      Pw[(quad * 4 + r) * PSTR + 16 + lo] = f2bf(e1);
    }
    const short8 pf = *(const short8*)(&Pw[lo * PSTR + quad * 8]);
#pragma unroll
    for (int nt = 0; nt < 4; ++nt)
      acc[nt] = __builtin_amdgcn_mfma_f32_16x16x32_bf16(pf, vfr[nt], acc[nt], 0, 0, 0);

    if (more) {
      const int nb = buf ^ 1;
      *(short8*)(&Ks[nb][r0 * KSTR + c0]) = nk0;
      *(short8*)(&Ks[nb][r1 * KSTR + c0]) = nk1;
      *(short8*)(&Vs[nb][r0 * KSTR + c0]) = nv0;
      *(short8*)(&Vs[nb][r1 * KSTR + c0]) = nv1;
    }
  }

#pragma unroll
  for (int d = 1; d < 16; d <<= 1) {
#pragma unroll
    for (int r = 0; r < 4; ++r) lsum[r] += __shfl_xor(lsum[r], d);
  }

  if (wk == 1) {
#pragma unroll
    for (int nt = 0; nt < 4; ++nt) Red[wr][nt][lane] = acc[nt];
    Red[wr][4][lane] = (floatx4){lsum[0], lsum[1], lsum[2], lsum[3]};
  }
  __syncthreads();
  if (wk == 0) {
    const floatx4 lp = Red[wr][4][lane];
    const int rowb = q0 + wr * 16 + quad * 4;
#pragma unroll
    for (int nt = 0; nt < 4; ++nt) {
      const floatx4 o = acc[nt] + Red[wr][nt][lane];
#pragma unroll
      for (int r = 0; r < 4; ++r)
        out[((size_t)b * SEQ + rowb + r) * HD + nt * 16 + lo] =
            o[r] / (lsum[r] + lp[r]);
    }
  }
}

extern "C" void kernel_launch(void* const* d_in, const int* in_sizes, int n_in,
                              void* d_out, int out_size, void* d_ws, size_t ws_size,
                              hipStream_t stream) {
  const float* x  = (const float*)d_in[0];
  const float* Wq = (const float*)d_in[1];
  const float* Wk = (const float*)d_in[2];
  const float* Wv = (const float*)d_in[3];
  float* out = (float*)d_out;
  short* ws = (short*)d_ws;
  short* qbp = ws;
  short* kbp = ws + (size_t)ROWS * HD;
  short* vtp = ws + (size_t)2 * ROWS * HD;
  short* Wts = ws + (size_t)3 * ROWS * HD;   // 384 KB; total 6.68 MB <= ws_size

  wt_kernel<<<dim3(96), 256, 0, stream>>>(Wq, Wk, Wv, Wts);
  proj_kernel<<<dim3(ROWS / 32), 256, 0, stream>>>(x, Wts, qbp, kbp, vtp);
  attn_kernel<<<dim3(SEQ / 32, BATCH), 256, 0, stream>>>(qbp, kbp, vtp, out);
}